// Round 11
// baseline (155.592 us; speedup 1.0000x reference)
//
#include <hip/hip_runtime.h>

// confidence_maps: (8,6,4,512,512) f32; warp_masks: (8,1,512,512) f32;
// gauss_kernel: (1,1,5,5) f32.
// Output: mask (48,1,512,512) f32 + rate scalar = 12,582,913 floats.
//
// Validated invariants (rounds 1-10, absmax 0.0 x10):
//  - rate == 0.5 exactly; ego rows (l==0) all-ones, excluded from rate.
//  - max_c(sigmoid) == sigmoid(max_c); separable gaussian factorization.
//  - 20-bit keys; pstar = exact key cutoff from two-level exact counts;
//    band |k-pstar|<=KAPPA=3 resolved by exact-f64 (branchy m_val, 25-tap)
//    rank (value desc, index asc); R = K - A2 + cntAbove.
//
// Round-11 (occupancy fix of compute_kernel; R10 profile: 118us of 150,
// Occupancy 29% <- LDS 52.7KB = 3 blocks/CU, both pipes ~20%):
//  - ht LDS buffer deleted: vertical conv via per-thread rolling 5-reg
//    horizontal window over a contiguous 16-row column strip (-17.4 KB).
//  - hist1 shrunk to 256 bins (k>>12), 4-copy (4 KB); hist2 refines with
//    4096 sub-bins (k&4095) -> pstar still an exact 20-bit key.
//  - compute LDS ~22.7 KB -> 7 blocks/CU (28 waves, 87.5%).

#define NROWSEL 40
#define NPIX    262144
#define KSEL    131072
#define CAND_CAP 512
#define KAPPA    3
#define KSCALE   1048576.0f   // 2^20
#define KMAX     1048575.0f

// ---- workspace layout (bytes) ----
#define OFF_KEY  0ull                  // 40*262144 u32 = 41,943,040
#define OFF_H1   41943040ull           // 40*256 u32    =     40,960
#define OFF_H2   41984000ull           // 40*4096 u32   =    655,360
#define OFF_ST   42639360ull           // 40*2 int      =        320
#define OFF_CC   42639680ull           // 40 u32        =        160
#define OFF_CI   42639840ull           // 40*512 int    =     81,920
#define OFF_CK   42721760ull           // 40*512 u32    =     81,920
#define META_U32 174200                // (H1+H2+ST+CC)/4 = 696,800 B

// fast f32 m = sigmoid(max_c conf) * warp  (hot path, approximate)
__device__ __forceinline__ float m_val_f32(const float* __restrict__ confr,
                                           const float* __restrict__ warpr,
                                           int gy, int gx) {
  if (gy < 0 || gy >= 512 || gx < 0 || gx >= 512) return 0.0f;
  int off = gy * 512 + gx;
  float x0 = confr[off];
  float x1 = confr[NPIX + off];
  float x2 = confr[2 * NPIX + off];
  float x3 = confr[3 * NPIX + off];
  float mx = fmaxf(fmaxf(x0, x1), fmaxf(x2, x3));
  float s = 1.0f / (1.0f + expf(-mx));
  return s * warpr[off];
}

// exact f64 m (R1-R10 formula); used only in resolve.
__device__ __forceinline__ double m_val(const float* __restrict__ confr,
                                        const float* __restrict__ warpr,
                                        int gy, int gx) {
  if (gy < 0 || gy >= 512 || gx < 0 || gx >= 512) return 0.0;
  int off = gy * 512 + gx;
  float x0 = confr[off];
  float x1 = confr[NPIX + off];
  float x2 = confr[2 * NPIX + off];
  float x3 = confr[3 * NPIX + off];
  float mx = fmaxf(fmaxf(x0, x1), fmaxf(x2, x3));
  double s = 1.0 / (1.0 + exp(-(double)mx));
  return s * (double)warpr[off];
}

// Serial descending scan over 256 bins; call from ONE thread.
__device__ __forceinline__ void scan256(const unsigned* __restrict__ cs,
                                        unsigned cum0, int& bsel,
                                        unsigned& above) {
  unsigned cum = cum0;
  bsel = 0; above = cum0;
  for (int c = 255; c >= 0; --c) {
    if (cum + cs[c] >= (unsigned)KSEL) { bsel = c; above = cum; break; }
    cum += cs[c];
  }
}

// Descending scan over 4096 LDS bins; 256-chunk partials in red.
// Result valid on tid==0 only.
__device__ __forceinline__ void scan4096(const unsigned* __restrict__ hs,
                                         unsigned* __restrict__ red,
                                         int tid, unsigned cum0,
                                         int* bsel, unsigned* above) {
  unsigned s = 0;
#pragma unroll 4
  for (int k = 0; k < 16; ++k) s += hs[tid * 16 + k];
  red[tid] = s;
  __syncthreads();
  if (tid == 0) {
    unsigned cum = cum0;
    *bsel = 0; *above = cum0;
    for (int c = 255; c >= 0; --c) {
      if (cum + red[c] >= (unsigned)KSEL) {
        unsigned cc2 = cum;
        for (int k = 15; k >= 0; --k) {
          unsigned hv = hs[c * 16 + k];
          if (cc2 + hv >= (unsigned)KSEL) { *bsel = c * 16 + k; *above = cc2; break; }
          cc2 += hv;
        }
        break;
      }
      cum += red[c];
    }
  }
}

// K0: fill the 8 ego rows (l==0) with 1.0 AND zero selection metadata.
__global__ void ego_fill_kernel(float* __restrict__ out,
                                unsigned* __restrict__ meta) {
  int i = blockIdx.x * 256 + threadIdx.x;   // 524288 float4 units
  int b = i >> 16;
  int o4 = i & 65535;
  float4* p = (float4*)(out + (size_t)b * 6u * NPIX) + o4;
  *p = make_float4(1.f, 1.f, 1.f, 1.f);
  if (i < META_U32) meta[i] = 0u;
}

// K1: separable f32 conv with rolling horizontal window (no ht buffer) +
// u32 20-bit key store + fused 256-bin coarse histogram (k>>12), 4-copy.
// LDS ~22.7 KB -> 7 blocks/CU.
__global__ __launch_bounds__(256) void compute_kernel(
    const float* __restrict__ conf, const float* __restrict__ warp,
    const float* __restrict__ gk, unsigned* __restrict__ keys,
    unsigned* __restrict__ hist1) {
  const int blk = blockIdx.x;        // 40 * 64
  const int j = blk >> 6;            // row 0..39
  const int tile = blk & 63;         // 8x8 tiles of 64x64
  const int ty0 = (tile >> 3) << 6;
  const int tx0 = (tile & 7) << 6;
  const int b = j / 5;
  const int l = j % 5 + 1;
  const int rowg = b * 6 + l;
  const float* confr = conf + (size_t)rowg * 4u * NPIX;
  const float* warpr = warp + (size_t)b * NPIX;

  __shared__ float mt[68][68];       // 18496 B
  __shared__ unsigned lh[1024];      //  4096 B (256 bins x 4 copies)
  __shared__ float wr[5], wc[5];     // => ~22.7 KB total
  const int tid = threadIdx.x;
  if (tid < 5) {
    wr[tid] = gk[10 + tid];               // c * a_dx  (middle row)
    wc[tid] = gk[tid * 5 + 2] / gk[12];   // a_dy      (middle col / center)
  }
  for (int i = tid; i < 1024; i += 256) lh[i] = 0u;

  for (int i = tid; i < 68 * 68; i += 256) {
    int hy = i / 68, hx = i - hy * 68;
    mt[hy][hx] = m_val_f32(confr, warpr, ty0 + hy - 2, tx0 + hx - 2);
  }
  __syncthreads();

  const int txl = tid & 63;
  const int y0 = (tid >> 6) << 4;    // contiguous 16-row strip per thread
  const int cpy = tid & 3;
  unsigned* keyrow = keys + (size_t)j * NPIX;

#define HROW(r) ({ float a_ = mt[(r)][txl] * wr[0];            \
                   a_ = fmaf(wr[1], mt[(r)][txl + 1], a_);     \
                   a_ = fmaf(wr[2], mt[(r)][txl + 2], a_);     \
                   a_ = fmaf(wr[3], mt[(r)][txl + 3], a_);     \
                   fmaf(wr[4], mt[(r)][txl + 4], a_); })

  float h0 = HROW(y0);
  float h1 = HROW(y0 + 1);
  float h2 = HROW(y0 + 2);
  float h3 = HROW(y0 + 3);
  for (int yy = y0; yy < y0 + 16; ++yy) {
    float h4 = HROW(yy + 4);
    float acc = h0 * wc[0];
    acc = fmaf(wc[1], h1, acc);
    acc = fmaf(wc[2], h2, acc);
    acc = fmaf(wc[3], h3, acc);
    acc = fmaf(wc[4], h4, acc);
    unsigned k = (unsigned)fminf(fmaxf(acc * KSCALE, 0.0f), KMAX);
    keyrow[(ty0 + yy) * 512 + (tx0 + txl)] = k;
    atomicAdd(&lh[(k >> 12) * 4 + cpy], 1u);
    h0 = h1; h1 = h2; h2 = h3; h3 = h4;
  }
#undef HROW
  __syncthreads();
  if (tid < 256) {
    unsigned s = lh[tid * 4] + lh[tid * 4 + 1] + lh[tid * 4 + 2] + lh[tid * 4 + 3];
    if (s) atomicAdd(&hist1[j * 256 + tid], s);
  }
}

// K2: refine histogram (k&4095 for keys with k>>12 == b1), inline scan of
// hist1, 2-copy privatized.
__global__ __launch_bounds__(256) void hist2_kernel(
    const unsigned* __restrict__ keys, const unsigned* __restrict__ hist1,
    unsigned* __restrict__ hist2) {
  int blk = blockIdx.x;              // 40 * 32
  int j = blk >> 5, seg = blk & 31;  // 8192 keys per segment
  __shared__ unsigned hs[256];
  __shared__ unsigned lh[8192];      // 4096 bins x 2 copies = 32 KB
  __shared__ int s_b1;
  int tid = threadIdx.x;
  hs[tid] = hist1[j * 256 + tid];
  for (int i = tid; i < 8192; i += 256) lh[i] = 0u;
  __syncthreads();
  if (tid == 0) {
    int b1; unsigned A1;
    scan256(hs, 0u, b1, A1);
    s_b1 = b1;
  }
  __syncthreads();
  unsigned ub1 = (unsigned)s_b1;
  const uint4* kp = (const uint4*)(keys + (size_t)j * NPIX + seg * 8192);
  int c = tid & 1;
#pragma unroll
  for (int it = 0; it < 8; ++it) {
    uint4 k4 = kp[tid + it * 256];
    if ((k4.x >> 12) == ub1) atomicAdd(&lh[(k4.x & 4095u) * 2 + c], 1u);
    if ((k4.y >> 12) == ub1) atomicAdd(&lh[(k4.y & 4095u) * 2 + c], 1u);
    if ((k4.z >> 12) == ub1) atomicAdd(&lh[(k4.z & 4095u) * 2 + c], 1u);
    if ((k4.w >> 12) == ub1) atomicAdd(&lh[(k4.w & 4095u) * 2 + c], 1u);
  }
  __syncthreads();
  for (int i = tid; i < 4096; i += 256) {
    unsigned s = lh[i * 2] + lh[i * 2 + 1];
    if (s) atomicAdd(&hist2[j * 4096 + i], s);
  }
}

// K3: inline scans -> pstar (exact 20-bit key), A2; write decided mask bits;
// gather band candidates (|k - pstar| <= KAPPA).
__global__ __launch_bounds__(256) void mask_gather_kernel(
    const unsigned* __restrict__ keys, const unsigned* __restrict__ hist1,
    const unsigned* __restrict__ hist2, float* __restrict__ out,
    int* __restrict__ st, unsigned* __restrict__ ccount,
    int* __restrict__ cidx, unsigned* __restrict__ ckey) {
  int blk = blockIdx.x;              // 40 * 32
  int j = blk >> 5, seg = blk & 31;
  int b = j / 5, l = j % 5 + 1;
  int rowg = b * 6 + l;
  __shared__ unsigned hs[4096];      // 16 KB (hist1 uses first 256)
  __shared__ unsigned red[256];
  __shared__ int s_pstar;
  int tid = threadIdx.x;
  hs[tid] = hist1[j * 256 + tid];
  __syncthreads();
  int b1 = 0; unsigned A1 = 0;
  if (tid == 0) scan256(hs, 0u, b1, A1);   // b1/A1 live on tid 0 only
  __syncthreads();                          // tid0 done before overwrite
  for (int i = tid; i < 4096; i += 256) hs[i] = hist2[j * 4096 + i];
  __syncthreads();
  int b2; unsigned A2;
  scan4096(hs, red, tid, A1, &b2, &A2);     // valid on tid 0
  if (tid == 0) {
    s_pstar = (b1 << 12) | b2;
    if (seg == 0) { st[j * 2] = s_pstar; st[j * 2 + 1] = (int)A2; }
  }
  __syncthreads();
  int pstar = s_pstar;

  const uint4* kp = (const uint4*)(keys + (size_t)j * NPIX + seg * 8192);
  float4* o4 = (float4*)(out + (size_t)rowg * NPIX + seg * 8192);
#pragma unroll
  for (int it = 0; it < 8; ++it) {
    int q = tid + it * 256;
    uint4 k4 = kp[q];
    unsigned w[4] = {k4.x, k4.y, k4.z, k4.w};
    float4 mv;
    float* mf = (float*)&mv;
#pragma unroll
    for (int e = 0; e < 4; ++e) {
      int k = (int)w[e];
      mf[e] = k > pstar + KAPPA ? 1.f : 0.f;
      if (k >= pstar - KAPPA && k <= pstar + KAPPA) {
        unsigned s = atomicAdd(&ccount[j], 1u);
        if (s < CAND_CAP) {
          cidx[j * CAND_CAP + s] = seg * 8192 + q * 4 + e;
          ckey[j * CAND_CAP + s] = (unsigned)k;
        }
      }
    }
    o4[q] = mv;
  }
}

// K4: exact f64 eval of the ~15-30 band candidates (branchy m_val, 25-tap,
// R4/R10-proven), exact rank (value desc, index asc), scatter top-R + rate.
__global__ __launch_bounds__(256) void resolve_kernel(
    const float* __restrict__ conf, const float* __restrict__ warp,
    const float* __restrict__ gk, const int* __restrict__ st,
    const unsigned* __restrict__ ccount, const int* __restrict__ cidx,
    const unsigned* __restrict__ ckey, float* __restrict__ out) {
  int j = blockIdx.x;                // 40
  int b = j / 5, l = j % 5 + 1;
  int rowg = b * 6 + l;
  const float* confr = conf + (size_t)rowg * 4u * NPIX;
  const float* warpr = warp + (size_t)b * NPIX;
  __shared__ double vs[CAND_CAP];    // 4 KB
  __shared__ int ids[CAND_CAP];      // 2 KB
  __shared__ unsigned red[256];
  __shared__ double g[25];
  int tid = threadIdx.x;
  if (tid < 25) g[tid] = (double)gk[tid];
  int pstar = st[j * 2];
  int A2 = st[j * 2 + 1];
  int C = (int)min(ccount[j], (unsigned)CAND_CAP);
  __syncthreads();
  unsigned cnt = 0;
  for (int i = tid; i < C; i += 256) {
    int idx = cidx[j * CAND_CAP + i];
    cnt += (int)ckey[j * CAND_CAP + i] > pstar ? 1u : 0u;
    int y = idx >> 9, x = idx & 511;
    double acc = 0.0;
#pragma unroll
    for (int dy = 0; dy < 5; ++dy)
#pragma unroll
      for (int dx = 0; dx < 5; ++dx)
        acc = fma(g[dy * 5 + dx], m_val(confr, warpr, y + dy - 2, x + dx - 2), acc);
    vs[i] = acc;
    ids[i] = idx;
  }
  red[tid] = cnt;
  __syncthreads();
  for (int s = 128; s > 0; s >>= 1) {
    if (tid < s) red[tid] += red[tid + s];
    __syncthreads();
  }
  int R = KSEL - A2 + (int)red[0];
  for (int i = tid; i < C; i += 256) {
    double vi = vs[i];
    int ii = ids[i];
    int rank = 0;
    for (int q = 0; q < C; ++q) {
      double vq = vs[q];
      rank += (vq > vi) || (vq == vi && ids[q] < ii) ? 1 : 0;
    }
    if (rank < R) out[(size_t)rowg * NPIX + ii] = 1.0f;
  }
  if (j == 0 && tid == 0) out[12582912] = 0.5f;  // rate == 0.5 exactly
}

extern "C" void kernel_launch(void* const* d_in, const int* in_sizes, int n_in,
                              void* d_out, int out_size, void* d_ws, size_t ws_size,
                              hipStream_t stream) {
  const float* conf = (const float*)d_in[0];
  const float* warp = (const float*)d_in[1];
  const float* gk   = (const float*)d_in[2];
  float* out = (float*)d_out;
  char* ws = (char*)d_ws;

  unsigned* keys = (unsigned*)(ws + OFF_KEY);
  unsigned* h1   = (unsigned*)(ws + OFF_H1);
  unsigned* h2   = (unsigned*)(ws + OFF_H2);
  int*      st   = (int*)(ws + OFF_ST);
  unsigned* cc   = (unsigned*)(ws + OFF_CC);
  int*      ci   = (int*)(ws + OFF_CI);
  unsigned* ck   = (unsigned*)(ws + OFF_CK);

  // 5 kernels, 4 boundaries. No hipMemsetAsync.
  ego_fill_kernel<<<2048, 256, 0, stream>>>(out, h1);
  compute_kernel<<<NROWSEL * 64, 256, 0, stream>>>(conf, warp, gk, keys, h1);
  hist2_kernel<<<NROWSEL * 32, 256, 0, stream>>>(keys, h1, h2);
  mask_gather_kernel<<<NROWSEL * 32, 256, 0, stream>>>(keys, h1, h2, out, st, cc, ci, ck);
  resolve_kernel<<<NROWSEL, 256, 0, stream>>>(conf, warp, gk, st, cc, ci, ck, out);
}